// Round 1
// baseline (239.472 us; speedup 1.0000x reference)
//
#include <hip/hip_runtime.h>
#include <hip/hip_bf16.h>

typedef __attribute__((ext_vector_type(8))) short short8;
typedef __attribute__((ext_vector_type(4))) float floatx4;

#define TILE_M 128
#define LDS_STRIDE 264  // 256 shorts + 8 pad -> 528B row stride, 2-way max bank aliasing (free)

static __device__ __forceinline__ unsigned short f2bf(float x) {
    // round-to-nearest-even fp32 -> bf16 (inputs are finite normals)
    unsigned int u = __builtin_bit_cast(unsigned int, x);
    unsigned int r = (u + 0x7FFFu + ((u >> 16) & 1u)) >> 16;
    return (unsigned short)r;
}

// Convert gather tables fp32 -> bf16 once per call (ws is re-poisoned every launch).
__global__ void convert_tables(const float* __restrict__ zd, const float* __restrict__ zs,
                               int nd, int ns,
                               unsigned short* __restrict__ outd, unsigned short* __restrict__ outs) {
    int stride = gridDim.x * blockDim.x;
    int total = nd + ns;
    for (int i = blockIdx.x * blockDim.x + threadIdx.x; i < total; i += stride) {
        if (i < nd) outd[i] = f2bf(zd[i]);
        else        outs[i - nd] = f2bf(zs[i - nd]);
    }
}

// W1 [256 k][128 n] row-major fp32  ->  w1t [128 n][256 k] bf16 (B-fragment friendly)
__global__ void prep_w1(const float* __restrict__ W1, unsigned short* __restrict__ w1t) {
    int i = blockIdx.x * 256 + threadIdx.x;   // 0..32767
    int n = i >> 8;
    int k = i & 255;
    w1t[n * 256 + k] = f2bf(W1[k * 128 + n]);
}

__global__ __launch_bounds__(256) void edge_mlp(
    const unsigned short* __restrict__ zd, const unsigned short* __restrict__ zs,
    const int* __restrict__ row, const int* __restrict__ col,
    const unsigned short* __restrict__ w1t,
    const float* __restrict__ b1, const float* __restrict__ w2,
    const float* __restrict__ b2, float* __restrict__ out)
{
    __shared__ unsigned short lds_a[TILE_M * LDS_STRIDE];
    __shared__ float red[2][TILE_M];

    const int tid = threadIdx.x;
    const long ebase = (long)blockIdx.x * TILE_M;

    // ---- stage A tile: 128 edges x 256 bf16 (drug row ++ disease row), 16B/thread/iter ----
    #pragma unroll
    for (int i = 0; i < 16; ++i) {
        int c = tid + 256 * i;          // chunk id, 32 x 16B chunks per edge
        int e = c >> 5;
        int cc = c & 31;                // 0..15 drug half, 16..31 disease half
        int isdis = cc >> 4;
        int idx = isdis ? col[ebase + e] : row[ebase + e];
        const unsigned short* src = (isdis ? zs : zd) + (size_t)idx * 128 + (size_t)(cc & 15) * 8;
        short8 v = *reinterpret_cast<const short8*>(src);
        *reinterpret_cast<short8*>(&lds_a[e * LDS_STRIDE + cc * 8]) = v;
    }

    const int lane = tid & 63;
    const int wave = tid >> 6;
    const int mh = wave >> 1;   // M-half (0/1): edges [mh*64, mh*64+64)
    const int nh = wave & 1;    // N-half (0/1): hidden [nh*64, nh*64+64)
    const int l15 = lane & 15;
    const int quad = lane >> 4;

    float b1v[4], w2v[4];
    #pragma unroll
    for (int nt = 0; nt < 4; ++nt) {
        int n = nh * 64 + nt * 16 + l15;
        b1v[nt] = b1[n];
        w2v[nt] = w2[n];
    }

    __syncthreads();

    floatx4 acc[4][4];
    #pragma unroll
    for (int mt = 0; mt < 4; ++mt)
        #pragma unroll
        for (int nt = 0; nt < 4; ++nt)
            acc[mt][nt] = (floatx4)(0.0f);

    // ---- K loop: 8 slices of K=32; A from LDS, B from L2-hot w1t ----
    #pragma unroll
    for (int s = 0; s < 8; ++s) {
        short8 af[4], bf[4];
        #pragma unroll
        for (int mt = 0; mt < 4; ++mt) {
            int m = mh * 64 + mt * 16 + l15;            // A[m][k], m = lane&15
            af[mt] = *reinterpret_cast<const short8*>(&lds_a[m * LDS_STRIDE + s * 32 + quad * 8]);
        }
        #pragma unroll
        for (int nt = 0; nt < 4; ++nt) {
            int n = nh * 64 + nt * 16 + l15;            // B[k][n], n = lane&15
            bf[nt] = *reinterpret_cast<const short8*>(&w1t[n * 256 + s * 32 + quad * 8]);
        }
        #pragma unroll
        for (int mt = 0; mt < 4; ++mt)
            #pragma unroll
            for (int nt = 0; nt < 4; ++nt)
                acc[mt][nt] = __builtin_amdgcn_mfma_f32_16x16x32_bf16(af[mt], bf[nt], acc[mt][nt], 0, 0, 0);
    }

    // ---- fused epilogue: out[m] = sum_n relu(h[m][n]+b1[n]) * w2[n] ----
    // C layout: n = lane&15, m = quad*4 + reg
    float p[4][4];
    #pragma unroll
    for (int mt = 0; mt < 4; ++mt) {
        #pragma unroll
        for (int r = 0; r < 4; ++r) {
            float s = 0.f;
            #pragma unroll
            for (int nt = 0; nt < 4; ++nt) {
                float h = acc[mt][nt][r] + b1v[nt];
                h = h > 0.f ? h : 0.f;
                s += h * w2v[nt];
            }
            p[mt][r] = s;
        }
    }
    // reduce across the 16 lanes (n within tile); masks stay inside the 16-lane group
    #pragma unroll
    for (int mt = 0; mt < 4; ++mt) {
        #pragma unroll
        for (int r = 0; r < 4; ++r) {
            float v = p[mt][r];
            v += __shfl_xor(v, 1);
            v += __shfl_xor(v, 2);
            v += __shfl_xor(v, 4);
            v += __shfl_xor(v, 8);
            p[mt][r] = v;
        }
    }
    if (l15 == 0) {
        #pragma unroll
        for (int mt = 0; mt < 4; ++mt)
            #pragma unroll
            for (int r = 0; r < 4; ++r)
                red[nh][mh * 64 + mt * 16 + quad * 4 + r] = p[mt][r];
    }
    __syncthreads();
    if (tid < TILE_M)
        out[ebase + tid] = red[0][tid] + red[1][tid] + b2[0];
}

extern "C" void kernel_launch(void* const* d_in, const int* in_sizes, int n_in,
                              void* d_out, int out_size, void* d_ws, size_t ws_size,
                              hipStream_t stream) {
    const float* zd = (const float*)d_in[0];
    const float* zs = (const float*)d_in[1];
    const int*   row = (const int*)d_in[2];
    const int*   col = (const int*)d_in[3];
    const float* W1 = (const float*)d_in[4];
    const float* b1 = (const float*)d_in[5];
    const float* w2 = (const float*)d_in[6];
    const float* b2 = (const float*)d_in[7];
    float* out = (float*)d_out;

    const int nd = in_sizes[0];   // 10000*128
    const int ns = in_sizes[1];   // 15000*128
    const int E  = in_sizes[2];   // 1048576

    unsigned short* zd_b = (unsigned short*)d_ws;
    unsigned short* zs_b = zd_b + nd;
    unsigned short* w1t  = zs_b + ns;   // 128*256 bf16

    hipLaunchKernelGGL(convert_tables, dim3(1024), dim3(256), 0, stream,
                       zd, zs, nd, ns, zd_b, zs_b);
    hipLaunchKernelGGL(prep_w1, dim3(128), dim3(256), 0, stream, W1, w1t);

    const int nblocks = E / TILE_M;  // E = 1048576 -> 8192, exact
    hipLaunchKernelGGL(edge_mlp, dim3(nblocks), dim3(256), 0, stream,
                       zd_b, zs_b, row, col, w1t, b1, w2, b2, out);
}

// Round 2
// 225.319 us; speedup vs baseline: 1.0628x; 1.0628x over previous
//
#include <hip/hip_runtime.h>
#include <hip/hip_bf16.h>

typedef __attribute__((ext_vector_type(8))) short short8;
typedef __attribute__((ext_vector_type(4))) float floatx4;
typedef __attribute__((ext_vector_type(4))) float float4v;
typedef __attribute__((ext_vector_type(4))) unsigned short ushort4v;

#define TILE_M 64
#define LDS_STRIDE 264  // 256 shorts + 8 pad -> 528B row stride, 2-way max bank aliasing (free)

static __device__ __forceinline__ unsigned short f2bf(float x) {
    // round-to-nearest-even fp32 -> bf16 (inputs are finite normals)
    unsigned int u = __builtin_bit_cast(unsigned int, x);
    unsigned int r = (u + 0x7FFFu + ((u >> 16) & 1u)) >> 16;
    return (unsigned short)r;
}

// Vectorized fp32 -> bf16 conversion of both tables (4 elems/thread).
__global__ void convert_tables(const float* __restrict__ zd, const float* __restrict__ zs,
                               int nd4, int ns4,
                               unsigned short* __restrict__ outd, unsigned short* __restrict__ outs) {
    int stride = gridDim.x * blockDim.x;
    int total4 = nd4 + ns4;
    for (int i = blockIdx.x * blockDim.x + threadIdx.x; i < total4; i += stride) {
        const float* src;
        unsigned short* dst;
        int j;
        if (i < nd4) { src = zd; dst = outd; j = i; }
        else         { src = zs; dst = outs; j = i - nd4; }
        float4v v = *reinterpret_cast<const float4v*>(src + (size_t)j * 4);
        ushort4v o;
        o.x = f2bf(v.x); o.y = f2bf(v.y); o.z = f2bf(v.z); o.w = f2bf(v.w);
        *reinterpret_cast<ushort4v*>(dst + (size_t)j * 4) = o;
    }
}

// W1 [256 k][128 n] row-major fp32  ->  w1t [128 n][256 k] bf16 (B-fragment friendly)
__global__ void prep_w1(const float* __restrict__ W1, unsigned short* __restrict__ w1t) {
    int i = blockIdx.x * 256 + threadIdx.x;   // 0..32767
    int n = i >> 8;
    int k = i & 255;
    w1t[n * 256 + k] = f2bf(W1[k * 128 + n]);
}

__global__ __launch_bounds__(256, 4) void edge_mlp(
    const unsigned short* __restrict__ zd, const unsigned short* __restrict__ zs,
    const int* __restrict__ row, const int* __restrict__ col,
    const unsigned short* __restrict__ w1t,
    const float* __restrict__ b1, const float* __restrict__ w2,
    const float* __restrict__ b2, float* __restrict__ out)
{
    __shared__ unsigned short lds_a[TILE_M * LDS_STRIDE];   // 33 KiB
    __shared__ float red[4][TILE_M];                        // 1 KiB

    const int tid = threadIdx.x;
    const long ebase = (long)blockIdx.x * TILE_M;
    const int lane = tid & 63;
    const int wave = tid >> 6;      // wave = N-quarter: hidden units [wave*32, wave*32+32)
    const int l15 = lane & 15;
    const int quad = lane >> 4;

    // ---- preload ALL B fragments for this wave's N-quarter (16 KB -> 64 VGPRs) ----
    // Issued first so these L2 loads overlap the A-tile gather below.
    short8 bfrag[16];               // [s*2 + nt]
    #pragma unroll
    for (int s = 0; s < 8; ++s) {
        #pragma unroll
        for (int nt = 0; nt < 2; ++nt) {
            int n = wave * 32 + nt * 16 + l15;
            bfrag[s * 2 + nt] = *reinterpret_cast<const short8*>(&w1t[n * 256 + s * 32 + quad * 8]);
        }
    }

    // ---- stage A tile: 64 edges x 256 bf16 (drug row ++ disease row), 16B/thread/iter ----
    #pragma unroll
    for (int i = 0; i < 8; ++i) {
        int c = tid + 256 * i;          // chunk id: 32 x 16B chunks per edge
        int e = c >> 5;
        int cc = c & 31;                // 0..15 drug half, 16..31 disease half
        int isdis = cc >> 4;
        int idx = isdis ? col[ebase + e] : row[ebase + e];
        const unsigned short* src = (isdis ? zs : zd) + (size_t)idx * 128 + (size_t)(cc & 15) * 8;
        short8 v = *reinterpret_cast<const short8*>(src);
        *reinterpret_cast<short8*>(&lds_a[e * LDS_STRIDE + cc * 8]) = v;
    }

    __syncthreads();

    floatx4 acc[4][2];
    #pragma unroll
    for (int mt = 0; mt < 4; ++mt)
        #pragma unroll
        for (int nt = 0; nt < 2; ++nt)
            acc[mt][nt] = (floatx4)(0.0f);

    // ---- K loop: 8 slices of K=32; A from LDS, B already in registers ----
    #pragma unroll
    for (int s = 0; s < 8; ++s) {
        short8 af[4];
        #pragma unroll
        for (int mt = 0; mt < 4; ++mt) {
            int m = mt * 16 + l15;                       // A[m][k], m = lane&15
            af[mt] = *reinterpret_cast<const short8*>(&lds_a[m * LDS_STRIDE + s * 32 + quad * 8]);
        }
        #pragma unroll
        for (int mt = 0; mt < 4; ++mt)
            #pragma unroll
            for (int nt = 0; nt < 2; ++nt)
                acc[mt][nt] = __builtin_amdgcn_mfma_f32_16x16x32_bf16(af[mt], bfrag[s * 2 + nt], acc[mt][nt], 0, 0, 0);
    }

    // ---- fused epilogue: out[m] = sum_n relu(h[m][n]+b1[n]) * w2[n] ----
    float b1v[2], w2v[2];
    #pragma unroll
    for (int nt = 0; nt < 2; ++nt) {
        int n = wave * 32 + nt * 16 + l15;
        b1v[nt] = b1[n];
        w2v[nt] = w2[n];
    }

    // C layout: n = lane&15, m = quad*4 + reg
    float p[4][4];
    #pragma unroll
    for (int mt = 0; mt < 4; ++mt) {
        #pragma unroll
        for (int r = 0; r < 4; ++r) {
            float s = 0.f;
            #pragma unroll
            for (int nt = 0; nt < 2; ++nt) {
                float h = acc[mt][nt][r] + b1v[nt];
                h = h > 0.f ? h : 0.f;
                s += h * w2v[nt];
            }
            p[mt][r] = s;
        }
    }
    // reduce across the 16 lanes (n within tile); masks stay inside the 16-lane group
    #pragma unroll
    for (int mt = 0; mt < 4; ++mt) {
        #pragma unroll
        for (int r = 0; r < 4; ++r) {
            float v = p[mt][r];
            v += __shfl_xor(v, 1);
            v += __shfl_xor(v, 2);
            v += __shfl_xor(v, 4);
            v += __shfl_xor(v, 8);
            p[mt][r] = v;
        }
    }
    if (l15 == 0) {
        #pragma unroll
        for (int mt = 0; mt < 4; ++mt)
            #pragma unroll
            for (int r = 0; r < 4; ++r)
                red[wave][mt * 16 + quad * 4 + r] = p[mt][r];
    }
    __syncthreads();
    if (tid < TILE_M)
        out[ebase + tid] = red[0][tid] + red[1][tid] + red[2][tid] + red[3][tid] + b2[0];
}

extern "C" void kernel_launch(void* const* d_in, const int* in_sizes, int n_in,
                              void* d_out, int out_size, void* d_ws, size_t ws_size,
                              hipStream_t stream) {
    const float* zd = (const float*)d_in[0];
    const float* zs = (const float*)d_in[1];
    const int*   row = (const int*)d_in[2];
    const int*   col = (const int*)d_in[3];
    const float* W1 = (const float*)d_in[4];
    const float* b1 = (const float*)d_in[5];
    const float* w2 = (const float*)d_in[6];
    const float* b2 = (const float*)d_in[7];
    float* out = (float*)d_out;

    const int nd = in_sizes[0];   // 10000*128
    const int ns = in_sizes[1];   // 15000*128
    const int E  = in_sizes[2];   // 1048576

    unsigned short* zd_b = (unsigned short*)d_ws;
    unsigned short* zs_b = zd_b + nd;
    unsigned short* w1t  = zs_b + ns;   // 128*256 bf16

    int total4 = (nd + ns) / 4;
    int cgrid = (total4 + 255) / 256;
    if (cgrid > 2048) cgrid = 2048;
    hipLaunchKernelGGL(convert_tables, dim3(cgrid), dim3(256), 0, stream,
                       zd, zs, nd / 4, ns / 4, zd_b, zs_b);
    hipLaunchKernelGGL(prep_w1, dim3(128), dim3(256), 0, stream, W1, w1t);

    const int nblocks = E / TILE_M;  // 1048576 / 64 = 16384, exact
    hipLaunchKernelGGL(edge_mlp, dim3(nblocks), dim3(256), 0, stream,
                       zd_b, zs_b, row, col, w1t, b1, w2, b2, out);
}